// Round 16
// baseline (448.984 us; speedup 1.0000x reference)
//
#include <hip/hip_runtime.h>
#include <math.h>
#include <stdint.h>

// Problem constants
#define TT 4
#define BB 16
#define CC 256
#define NN 1024
#define NT 16        // spatial positions per block
#define EPSF 1e-5f
// Rescue margin: 3-product q/k GEMM error sigma ~3e-6; 6e-5 = ~14 sigma
// (validated R13-R15). Margin-flagged decisions recompute with the exact
// fp32 chain (bit-identical to reference) -> final spikes exact regardless.
#define EPS_R 6e-5f

typedef __attribute__((ext_vector_type(8))) short short8;  // 8 bf16 (4 VGPR)
typedef __attribute__((ext_vector_type(4))) float f32x4;
#define MFMA __builtin_amdgcn_mfma_f32_16x16x32_bf16

// LDS: 2 X planes (hi, mid) + small fp32 staging scratch = 75008 B.
// 2 blocks/CU by LDS; NO register cap (R14/R15 lesson: a 64-VGPR
// launch-bounds cap makes the allocator spill catastrophically; R13's
// fused structure compiles to ~56 VGPR uncapped, which fits 8 waves/SIMD
// naturally).
#define XCH 1040          // X-plane chunk stride: 1024 + 16 bank-shift
#define XPL 33280         // X plane = 32 chunks * 1040
#define LDS_X 0
#define LDS_XF 66560      // scratch: 32c * 66dw * 4B = 8448; reused for dsum
#define LDS_TOT 75008

// bf16 split helpers (RNE). v == hi + mid + lo EXACTLY.
__device__ __forceinline__ uint32_t f2bf(float x) {
  const uint32_t u = __float_as_uint(x);
  return (u + 0x7FFFu + ((u >> 16) & 1u)) >> 16;
}
__device__ __forceinline__ float bf2f(uint32_t b) { return __uint_as_float(b << 16); }

// ---------------- weight pre-split kernel (layout identical R10-R15) --------
// ws bytes: mat*393216 + p*131072 + ot*8192 + kk*1024 + lane*16.
// Lane l: w_plane[o = ot*16 + (l&15)][k = kk*32 + (l>>4)*8 .. +8]
__global__ __launch_bounds__(256)
void wsplit2(const float* __restrict__ qw, const float* __restrict__ kw,
             const float* __restrict__ pw, uint16_t* __restrict__ ws) {
  const int gid = blockIdx.x * 256 + threadIdx.x;   // 24576 threads
  const int mat = gid >> 13;
  const int ot  = (gid >> 9) & 15;
  const int kk  = (gid >> 6) & 7;
  const int l   = gid & 63;
  const float* w = (mat == 0 ? qw : (mat == 1 ? kw : pw));
  const int o  = ot * 16 + (l & 15);
  const int k0 = kk * 32 + (l >> 4) * 8;
  uint16_t ph[8], pm[8], pl[8];
  #pragma unroll
  for (int j = 0; j < 8; ++j) {
    const float v = w[(size_t)o * CC + k0 + j];
    const uint32_t bh = f2bf(v);
    const float r1 = v - bf2f(bh);       // exact
    const uint32_t bm = f2bf(r1);
    const float r2 = r1 - bf2f(bm);      // exact
    ph[j] = (uint16_t)bh; pm[j] = (uint16_t)bm; pl[j] = (uint16_t)f2bf(r2);
  }
  const size_t base = ((size_t)mat * 3 * 65536) + ((size_t)ot * 4096) +
                      kk * 512 + l * 8;            // uint16 units
  *(uint4*)(ws + base)          = *(const uint4*)ph;
  *(uint4*)(ws + base + 65536)  = *(const uint4*)pm;
  *(uint4*)(ws + base + 131072) = *(const uint4*)pl;
}

// LIF (tau=2, hard reset) with decision-margin tracking.
__device__ __forceinline__ void lif4m(float q0, float q1, float q2, float q3,
                                      float th, float s[4], float& mg) {
  const float qq[4] = {q0, q1, q2, q3};
  float v = 0.f;
  #pragma unroll
  for (int t = 0; t < 4; ++t) {
    const float h = v + (qq[t] - v) * 0.5f;
    const float d = h - th;
    mg = fminf(mg, fabsf(d));
    const bool f = d >= 0.f;
    s[t] = f ? 1.f : 0.f;
    v = f ? 0.f : h;
  }
}

// Exact-chain rescue (q/k): exact fp32 x straight from GLOBAL (validated
// R14/R15), strict ascending-c fmaf chain per t — bit-identical to reference.
__device__ __forceinline__ void rescue3g(const float* __restrict__ wrow,
                                         const float* __restrict__ x,
                                         int b, int n0, int ln, float sv[4]) {
  #pragma unroll
  for (int t = 0; t < 4; ++t) {
    const float* xg = x + (size_t)(t * BB + b) * CC * NN + n0 + ln;
    float s = 0.f;
    #pragma unroll 1
    for (int c = 0; c < CC; ++c) s = fmaf(wrow[c], xg[(size_t)c * NN], s);
    sv[t] = s;
  }
}

// Exact-chain rescue (proj): x_one is binary, exact in LDS plane 0.
__device__ __forceinline__ void rescue1(const float* __restrict__ wrow,
                                        const char* lds, int ln, float sv[4]) {
  #pragma unroll
  for (int t = 0; t < 4; ++t) sv[t] = 0.f;
  #pragma unroll 1
  for (int c8 = 0; c8 < 32; ++c8) {
    const float4 wa = *(const float4*)(wrow + c8 * 8);
    const float4 wb = *(const float4*)(wrow + c8 * 8 + 4);
    const float wl_[8] = {wa.x, wa.y, wa.z, wa.w, wb.x, wb.y, wb.z, wb.w};
    #pragma unroll
    for (int t = 0; t < 4; ++t) {
      const int off = c8 * XCH + (t * 16 + ln) * 16;
      const short8 h = *(const short8*)(lds + LDS_X + off);
      float s = sv[t];
      #pragma unroll
      for (int j = 0; j < 8; ++j)
        s = fmaf(wl_[j], bf2f((uint16_t)h[j]), s);
      sv[t] = s;
    }
  }
}

// 1024 thr = 16 waves; wave = one 16-channel o-tile (ot).
// acc[nt][r]: o = ot*16 + g*4 + r, t = nt, n = ln -> LIF shuffle-free.
// Fused q+k (shared b reads), 3 products {wm*xh, wh*xm, wh*xh}; proj 2
// products. Identical product order to R13 -> spikes bit-exact.
__global__ __launch_bounds__(1024, 4)
void pushpull_mfma9(const float* __restrict__ x,
                    const float* __restrict__ q_w, const float* __restrict__ q_gamma,
                    const float* __restrict__ q_beta, const float* __restrict__ q_mean,
                    const float* __restrict__ q_var,
                    const float* __restrict__ k_w, const float* __restrict__ k_gamma,
                    const float* __restrict__ k_beta, const float* __restrict__ k_mean,
                    const float* __restrict__ k_var,
                    const float* __restrict__ proj_w, const float* __restrict__ proj_b,
                    const float* __restrict__ p_gamma, const float* __restrict__ p_beta,
                    const float* __restrict__ p_mean, const float* __restrict__ p_var,
                    const uint16_t* __restrict__ ws, float* __restrict__ out) {
  __shared__ __align__(16) char lds[LDS_TOT];

  const int tid  = threadIdx.x;
  const int bid  = (int)blockIdx.x;
  const int lid  = ((bid & 7) << 7) | (bid >> 3);   // bijective XCD swizzle
  const int b    = lid >> 6;
  const int n0   = (lid & 63) * NT;
  const int lane = tid & 63;
  const int ln   = tid & 15;
  const int g    = (tid >> 4) & 3;
  const int ot   = tid >> 6;           // wave index = o-tile (16 channels)

  // ---- stage x in 8 quarter-passes: fp32 -> {hi, mid} planes ----
  float* xf = (float*)(lds + LDS_XF);
  #pragma unroll 1
  for (int ps = 0; ps < 8; ++ps) {
    if (tid < 512) {                   // 32c x 4t x 4 float4 = 512 loads
      const int cl = tid >> 4, t = (tid >> 2) & 3, n4 = (tid & 3) * 4;
      const float4 v = *(const float4*)(
          x + ((size_t)(t * BB + b) * CC + ps * 32 + cl) * NN + n0 + n4);
      *(float4*)(xf + cl * 66 + t * 16 + n4) = v;
    }
    __syncthreads();
    if (tid < 256) {                   // 4 chunks x 64 cols
      const int chL = tid >> 6, col = tid & 63;
      uint16_t ph[8], pm[8];
      #pragma unroll
      for (int j = 0; j < 8; ++j) {
        const float v = xf[(chL * 8 + j) * 66 + col];
        const uint32_t bh = f2bf(v);
        pm[j] = (uint16_t)f2bf(v - bf2f(bh));
        ph[j] = (uint16_t)bh;
      }
      const int ca = (ps * 4 + chL) * XCH + col * 16;
      *(uint4*)(lds + LDS_X + ca) = *(const uint4*)ph;
      *(uint4*)(lds + LDS_X + XPL + ca) = *(const uint4*)pm;
    }
    __syncthreads();
  }

  const char* wq = (const char*)ws;                       // q planes
  const char* wk = (const char*)ws + 393216;              // k planes
  const char* wp = (const char*)ws + 786432;              // proj planes

  // ====== fused q + k GEMM: 3 products each, shared b reads, A/B prefetch ===
  f32x4 aq[4], ak[4];
  #pragma unroll
  for (int nt = 0; nt < 4; ++nt) { aq[nt] = (f32x4)0.f; ak[nt] = (f32x4)0.f; }

  short8 qA[2], kA[2], qB[2], kB[2];
#define LOADQK(DQ, DK, KK) do {                                               \
    _Pragma("unroll")                                                         \
    for (int p = 0; p < 2; ++p) {                                             \
      const size_t foff = (size_t)p * 131072 + (size_t)ot * 8192 +            \
                          (size_t)(KK) * 1024 + (size_t)lane * 16;            \
      DQ[p] = *(const short8*)(wq + foff);                                    \
      DK[p] = *(const short8*)(wk + foff);                                    \
    }                                                                         \
  } while (0)
  // products small->large: wm*xh, wh*xm, wh*xh (identical order to R13)
#define STEPQK(FQ, FK, KK) do {                                               \
    __builtin_amdgcn_s_setprio(1);                                            \
    _Pragma("unroll")                                                         \
    for (int nt = 0; nt < 4; ++nt) {                                          \
      const int boff = ((KK) * 4 + g) * XCH + (nt * 16 + ln) * 16;            \
      const short8 b0 = *(const short8*)(lds + LDS_X + boff);                 \
      const short8 b1 = *(const short8*)(lds + LDS_X + XPL + boff);           \
      aq[nt] = MFMA(FQ[1], b0, aq[nt], 0, 0, 0);                              \
      aq[nt] = MFMA(FQ[0], b1, aq[nt], 0, 0, 0);                              \
      aq[nt] = MFMA(FQ[0], b0, aq[nt], 0, 0, 0);                              \
      ak[nt] = MFMA(FK[1], b0, ak[nt], 0, 0, 0);                              \
      ak[nt] = MFMA(FK[0], b1, ak[nt], 0, 0, 0);                              \
      ak[nt] = MFMA(FK[0], b0, ak[nt], 0, 0, 0);                              \
    }                                                                         \
    __builtin_amdgcn_s_setprio(0);                                            \
  } while (0)

  LOADQK(qA, kA, 0);
  #pragma unroll 1
  for (int kk2 = 0; kk2 < 4; ++kk2) {
    const int kk = kk2 * 2;
    LOADQK(qB, kB, kk + 1);
    STEPQK(qA, kA, kk);
    if (kk2 < 3) LOADQK(qA, kA, kk + 2);
    STEPQK(qB, kB, kk + 1);
  }

  // ---- q epilogue: BN + push/pull LIF (+rescue) -> dsum[t] ----
  float dsum[4] = {0.f, 0.f, 0.f, 0.f};
  #pragma unroll
  for (int r = 0; r < 4; ++r) {
    const int o = ot * 16 + g * 4 + r;
    const float inv = q_gamma[o] / sqrtf(q_var[o] + EPSF);
    const float mn = q_mean[o], bt = q_beta[o];
    float qv[4];
    #pragma unroll
    for (int t = 0; t < 4; ++t) qv[t] = (aq[t][r] - mn) * inv + bt;
    float se[4], si[4], mg = 1e30f;
    lif4m(qv[0], qv[1], qv[2], qv[3], 1.0f, se, mg);
    lif4m(-qv[0], -qv[1], -qv[2], -qv[3], 1.0f, si, mg);
    if (__builtin_expect(mg < EPS_R, 0)) {
      float qx[4];
      rescue3g(q_w + (size_t)o * CC, x, b, n0, ln, qx);
      #pragma unroll
      for (int t = 0; t < 4; ++t) qx[t] = (qx[t] - mn) * inv + bt;
      float m2 = 1e30f;
      lif4m(qx[0], qx[1], qx[2], qx[3], 1.0f, se, m2);
      lif4m(-qx[0], -qx[1], -qx[2], -qx[3], 1.0f, si, m2);
    }
    #pragma unroll
    for (int t = 0; t < 4; ++t) dsum[t] += se[t] - si[t];   // exact ints
  }
  // reduce over the wave's 4 g-groups (16 channels), exact ints
  #pragma unroll
  for (int t = 0; t < 4; ++t) {
    float v = dsum[t];
    v += __shfl_xor(v, 16);
    v += __shfl_xor(v, 32);
    dsum[t] = v;
  }

  // ---- k epilogue: BN + LIF (+rescue) -> spike bits ----
  unsigned kb = 0u;   // bit r*4+t
  #pragma unroll
  for (int r = 0; r < 4; ++r) {
    const int o = ot * 16 + g * 4 + r;
    const float inv = k_gamma[o] / sqrtf(k_var[o] + EPSF);
    const float mn = k_mean[o], bt = k_beta[o];
    float kv[4];
    #pragma unroll
    for (int t = 0; t < 4; ++t) kv[t] = (ak[t][r] - mn) * inv + bt;
    float sk[4], mg = 1e30f;
    lif4m(kv[0], kv[1], kv[2], kv[3], 1.0f, sk, mg);
    if (__builtin_expect(mg < EPS_R, 0)) {
      float kx[4];
      rescue3g(k_w + (size_t)o * CC, x, b, n0, ln, kx);
      #pragma unroll
      for (int t = 0; t < 4; ++t) kx[t] = (kx[t] - mn) * inv + bt;
      float m2 = 1e30f;
      lif4m(kx[0], kx[1], kx[2], kx[3], 1.0f, sk, m2);
    }
    #pragma unroll
    for (int t = 0; t < 4; ++t) kb |= (sk[t] != 0.f) ? (1u << (r * 4 + t)) : 0u;
  }

  // ---- head pair-reduce via LDS scratch (staging long finished) ----
  float* db = (float*)(lds + LDS_XF);   // [wave 16][ln 16][t 4]
  __syncthreads();                      // all plane-0/1 GEMM reads done
  if (g == 0) {
    #pragma unroll
    for (int t = 0; t < 4; ++t) db[(ot * 16 + ln) * 4 + t] = dsum[t];
  }
  __syncthreads();
  float at[4];
  {
    float tot[4];
    #pragma unroll
    for (int t = 0; t < 4; ++t)
      tot[t] = dsum[t] + db[((ot ^ 1) * 16 + ln) * 4 + t];   // exact ints
    float mgd = 1e30f;
    lif4m(tot[0], tot[1], tot[2], tot[3], 0.5f, at, mgd);    // exact dyadics
  }

  // ---- x_one = attn & k_s (binary bf16) -> plane 0 ----
  {
    const int chunk = ot * 2 + (g >> 1);
    const int j0 = (g & 1) * 4;
    #pragma unroll
    for (int t = 0; t < 4; ++t) {
      unsigned long long wbits = 0ull;
      #pragma unroll
      for (int r = 0; r < 4; ++r)
        if (((kb >> (r * 4 + t)) & 1u) && at[t] != 0.f)
          wbits |= 0x3F80ull << (r * 16);
      *(unsigned long long*)(lds + LDS_X + chunk * XCH +
                             (t * 16 + ln) * 16 + j0 * 2) = wbits;
    }
  }
  __syncthreads();   // x_one visible

  // ====== proj GEMM: 2 products {wm, wh} x binary x_one (plane 0) ======
  f32x4 ap[4];
  #pragma unroll
  for (int nt = 0; nt < 4; ++nt) ap[nt] = (f32x4)0.f;

  short8 pA[2], pB[2];
#define LOADP(DP, KK) do {                                                    \
    _Pragma("unroll")                                                         \
    for (int p = 0; p < 2; ++p)                                               \
      DP[p] = *(const short8*)(wp + (size_t)p * 131072 + (size_t)ot * 8192 +  \
                               (size_t)(KK) * 1024 + (size_t)lane * 16);      \
  } while (0)
#define STEPP(FP, KK) do {                                                    \
    __builtin_amdgcn_s_setprio(1);                                            \
    _Pragma("unroll")                                                         \
    for (int nt = 0; nt < 4; ++nt) {                                          \
      const short8 b0 = *(const short8*)(lds + LDS_X +                        \
                        ((KK) * 4 + g) * XCH + (nt * 16 + ln) * 16);          \
      ap[nt] = MFMA(FP[1], b0, ap[nt], 0, 0, 0);                              \
      ap[nt] = MFMA(FP[0], b0, ap[nt], 0, 0, 0);                              \
    }                                                                         \
    __builtin_amdgcn_s_setprio(0);                                            \
  } while (0)

  LOADP(pA, 0);
  #pragma unroll 1
  for (int kk2 = 0; kk2 < 4; ++kk2) {
    const int kk = kk2 * 2;
    LOADP(pB, kk + 1);
    STEPP(pA, kk);
    if (kk2 < 3) LOADP(pA, kk + 2);
    STEPP(pB, kk + 1);
  }

  // ---- proj epilogue: bias + BN + LIF (+rescue) + store ----
  #pragma unroll
  for (int r = 0; r < 4; ++r) {
    const int o = ot * 16 + g * 4 + r;
    const float inv = p_gamma[o] / sqrtf(p_var[o] + EPSF);
    const float mn = p_mean[o], bt = p_beta[o], pb = proj_b[o];
    float pv[4];
    #pragma unroll
    for (int t = 0; t < 4; ++t) pv[t] = ((ap[t][r] + pb) - mn) * inv + bt;
    float sp[4], mg = 1e30f;
    lif4m(pv[0], pv[1], pv[2], pv[3], 1.0f, sp, mg);
    if (__builtin_expect(mg < EPS_R, 0)) {
      float px[4];
      rescue1(proj_w + (size_t)o * CC, lds, ln, px);
      #pragma unroll
      for (int t = 0; t < 4; ++t) px[t] = ((px[t] + pb) - mn) * inv + bt;
      float m2 = 1e30f;
      lif4m(px[0], px[1], px[2], px[3], 1.0f, sp, m2);
    }
    #pragma unroll
    for (int t = 0; t < 4; ++t)
      out[((size_t)(t * BB + b) * CC + o) * NN + n0 + ln] = sp[t];
  }
}

extern "C" void kernel_launch(void* const* d_in, const int* in_sizes, int n_in,
                              void* d_out, int out_size, void* d_ws, size_t ws_size,
                              hipStream_t stream) {
  const float* x       = (const float*)d_in[0];
  const float* q_w     = (const float*)d_in[1];
  const float* q_gamma = (const float*)d_in[2];
  const float* q_beta  = (const float*)d_in[3];
  const float* q_mean  = (const float*)d_in[4];
  const float* q_var   = (const float*)d_in[5];
  const float* k_w     = (const float*)d_in[6];
  const float* k_gamma = (const float*)d_in[7];
  const float* k_beta  = (const float*)d_in[8];
  const float* k_mean  = (const float*)d_in[9];
  const float* k_var   = (const float*)d_in[10];
  const float* proj_w  = (const float*)d_in[11];
  const float* proj_b  = (const float*)d_in[12];
  const float* p_gamma = (const float*)d_in[13];
  const float* p_beta  = (const float*)d_in[14];
  const float* p_mean  = (const float*)d_in[15];
  const float* p_var   = (const float*)d_in[16];
  float* out = (float*)d_out;
  uint16_t* wsp = (uint16_t*)d_ws;   // 1.125 MB split-weight fragment planes

  wsplit2<<<96, 256, 0, stream>>>(q_w, k_w, proj_w, wsp);
  pushpull_mfma9<<<BB * (NN / NT), 1024, 0, stream>>>(
      x, q_w, q_gamma, q_beta, q_mean, q_var,
      k_w, k_gamma, k_beta, k_mean, k_var,
      proj_w, proj_b, p_gamma, p_beta, p_mean, p_var, wsp, out);
}

// Round 17
// 124.631 us; speedup vs baseline: 3.6025x; 3.6025x over previous
//
#include <hip/hip_runtime.h>
#include <math.h>
#include <stdint.h>

// Problem constants
#define TT 4
#define BB 16
#define CC 256
#define NN 1024
#define NT 16        // spatial positions per block
#define EPSF 1e-5f
// Rescue margin: 3-product q/k GEMM error sigma ~3e-6; 6e-5 = ~14 sigma
// (validated R13-R16). Margin-flagged decisions recompute with the exact
// fp32 chain (bit-identical to reference) -> final spikes exact regardless.
#define EPS_R 6e-5f

typedef __attribute__((ext_vector_type(8))) short short8;  // 8 bf16 (4 VGPR)
typedef __attribute__((ext_vector_type(4))) float f32x4;
#define MFMA __builtin_amdgcn_mfma_f32_16x16x32_bf16

// LDS: 2 X planes (hi, mid) + small fp32 staging scratch = 75008 B.
// 2 blocks/CU by LDS; no launch-bounds register cap (R14/R15 lesson).
#define XCH 1040          // X-plane chunk stride: 1024 + 16 bank-shift
#define XPL 33280         // X plane = 32 chunks * 1040
#define LDS_X 0
#define LDS_XF 66560      // scratch: 32c * 66dw * 4B = 8448; reused for dsum
#define LDS_TOT 75008

// bf16 split helpers (RNE).
__device__ __forceinline__ uint32_t f2bf(float x) {
  const uint32_t u = __float_as_uint(x);
  return (u + 0x7FFFu + ((u >> 16) & 1u)) >> 16;
}
__device__ __forceinline__ float bf2f(uint32_t b) { return __uint_as_float(b << 16); }

// ---------------- weight pre-split kernel (layout identical R10-R16) --------
// ws bytes: mat*393216 + p*131072 + ot*8192 + kk*1024 + lane*16.
// Lane l: w_plane[o = ot*16 + (l&15)][k = kk*32 + (l>>4)*8 .. +8]
__global__ __launch_bounds__(256)
void wsplit2(const float* __restrict__ qw, const float* __restrict__ kw,
             const float* __restrict__ pw, uint16_t* __restrict__ ws) {
  const int gid = blockIdx.x * 256 + threadIdx.x;   // 24576 threads
  const int mat = gid >> 13;
  const int ot  = (gid >> 9) & 15;
  const int kk  = (gid >> 6) & 7;
  const int l   = gid & 63;
  const float* w = (mat == 0 ? qw : (mat == 1 ? kw : pw));
  const int o  = ot * 16 + (l & 15);
  const int k0 = kk * 32 + (l >> 4) * 8;
  uint16_t ph[8], pm[8], pl[8];
  #pragma unroll
  for (int j = 0; j < 8; ++j) {
    const float v = w[(size_t)o * CC + k0 + j];
    const uint32_t bh = f2bf(v);
    const float r1 = v - bf2f(bh);       // exact
    const uint32_t bm = f2bf(r1);
    const float r2 = r1 - bf2f(bm);      // exact
    ph[j] = (uint16_t)bh; pm[j] = (uint16_t)bm; pl[j] = (uint16_t)f2bf(r2);
  }
  const size_t base = ((size_t)mat * 3 * 65536) + ((size_t)ot * 4096) +
                      kk * 512 + l * 8;            // uint16 units
  *(uint4*)(ws + base)          = *(const uint4*)ph;
  *(uint4*)(ws + base + 65536)  = *(const uint4*)pm;
  *(uint4*)(ws + base + 131072) = *(const uint4*)pl;
}

// LIF (tau=2, hard reset) with decision-margin tracking.
__device__ __forceinline__ void lif4m(float q0, float q1, float q2, float q3,
                                      float th, float s[4], float& mg) {
  const float qq[4] = {q0, q1, q2, q3};
  float v = 0.f;
  #pragma unroll
  for (int t = 0; t < 4; ++t) {
    const float h = v + (qq[t] - v) * 0.5f;
    const float d = h - th;
    mg = fminf(mg, fabsf(d));
    const bool f = d >= 0.f;
    s[t] = f ? 1.f : 0.f;
    v = f ? 0.f : h;
  }
}

// Exact-chain rescue (proj): x_one is binary, exact in LDS plane 0. Fast.
__device__ __forceinline__ void rescue1(const float* __restrict__ wrow,
                                        const char* lds, int ln, float sv[4]) {
  #pragma unroll
  for (int t = 0; t < 4; ++t) sv[t] = 0.f;
  #pragma unroll 1
  for (int c8 = 0; c8 < 32; ++c8) {
    const float4 wa = *(const float4*)(wrow + c8 * 8);
    const float4 wb = *(const float4*)(wrow + c8 * 8 + 4);
    const float wl_[8] = {wa.x, wa.y, wa.z, wa.w, wb.x, wb.y, wb.z, wb.w};
    #pragma unroll
    for (int t = 0; t < 4; ++t) {
      const int off = c8 * XCH + (t * 16 + ln) * 16;
      const short8 h = *(const short8*)(lds + LDS_X + off);
      float s = sv[t];
      #pragma unroll
      for (int j = 0; j < 8; ++j)
        s = fmaf(wl_[j], bf2f((uint16_t)h[j]), s);
      sv[t] = s;
    }
  }
}

// Cooperative exact rescue chain (q/k): ALL 64 lanes recompute channel o for
// (t = lane>>4, col = n0 + (lane&15)) with the exact ascending-c fmaf chain
// on exact fp32 x from global. x reads coalesce (16 lanes share a 64B line);
// unroll-8 keeps 8 loads in flight. Numerically identical to the per-lane
// serial rescue validated in R14-R16 (absmax 0.0), ~100x faster.
__device__ __forceinline__ float coop_chain(const float* __restrict__ wrow,
                                            const float* __restrict__ x,
                                            int b, int n0, int lane) {
  const float* xg = x + (size_t)((lane >> 4) * BB + b) * CC * NN + n0 + (lane & 15);
  float s = 0.f;
  #pragma unroll 8
  for (int c = 0; c < CC; ++c) s = fmaf(wrow[c], xg[(size_t)c * NN], s);
  return s;
}

// 1024 thr = 16 waves; wave = one 16-channel o-tile (ot).
// acc[nt][r]: o = ot*16 + g*4 + r, t = nt, n = ln -> LIF shuffle-free.
// Fused q+k (shared b reads), 3 products {wm*xh, wh*xm, wh*xh}; proj 2
// products. Identical product order to R13-R16 -> spikes bit-exact.
__global__ __launch_bounds__(1024, 4)
void pushpull_mfma10(const float* __restrict__ x,
                     const float* __restrict__ q_w, const float* __restrict__ q_gamma,
                     const float* __restrict__ q_beta, const float* __restrict__ q_mean,
                     const float* __restrict__ q_var,
                     const float* __restrict__ k_w, const float* __restrict__ k_gamma,
                     const float* __restrict__ k_beta, const float* __restrict__ k_mean,
                     const float* __restrict__ k_var,
                     const float* __restrict__ proj_w, const float* __restrict__ proj_b,
                     const float* __restrict__ p_gamma, const float* __restrict__ p_beta,
                     const float* __restrict__ p_mean, const float* __restrict__ p_var,
                     const uint16_t* __restrict__ ws, float* __restrict__ out) {
  __shared__ __align__(16) char lds[LDS_TOT];

  const int tid  = threadIdx.x;
  const int bid  = (int)blockIdx.x;
  const int lid  = ((bid & 7) << 7) | (bid >> 3);   // bijective XCD swizzle
  const int b    = lid >> 6;
  const int n0   = (lid & 63) * NT;
  const int lane = tid & 63;
  const int ln   = tid & 15;
  const int g    = (tid >> 4) & 3;
  const int ot   = tid >> 6;           // wave index = o-tile (16 channels)

  // ---- stage x in 8 quarter-passes: fp32 -> {hi, mid} planes ----
  float* xf = (float*)(lds + LDS_XF);
  #pragma unroll 1
  for (int ps = 0; ps < 8; ++ps) {
    if (tid < 512) {                   // 32c x 4t x 4 float4 = 512 loads
      const int cl = tid >> 4, t = (tid >> 2) & 3, n4 = (tid & 3) * 4;
      const float4 v = *(const float4*)(
          x + ((size_t)(t * BB + b) * CC + ps * 32 + cl) * NN + n0 + n4);
      *(float4*)(xf + cl * 66 + t * 16 + n4) = v;
    }
    __syncthreads();
    if (tid < 256) {                   // 4 chunks x 64 cols
      const int chL = tid >> 6, col = tid & 63;
      uint16_t ph[8], pm[8];
      #pragma unroll
      for (int j = 0; j < 8; ++j) {
        const float v = xf[(chL * 8 + j) * 66 + col];
        const uint32_t bh = f2bf(v);
        pm[j] = (uint16_t)f2bf(v - bf2f(bh));
        ph[j] = (uint16_t)bh;
      }
      const int ca = (ps * 4 + chL) * XCH + col * 16;
      *(uint4*)(lds + LDS_X + ca) = *(const uint4*)ph;
      *(uint4*)(lds + LDS_X + XPL + ca) = *(const uint4*)pm;
    }
    __syncthreads();
  }

  const char* wq = (const char*)ws;                       // q planes
  const char* wk = (const char*)ws + 393216;              // k planes
  const char* wp = (const char*)ws + 786432;              // proj planes

  // ====== fused q + k GEMM: 3 products each, shared b reads, A/B prefetch ===
  f32x4 aq[4], ak[4];
  #pragma unroll
  for (int nt = 0; nt < 4; ++nt) { aq[nt] = (f32x4)0.f; ak[nt] = (f32x4)0.f; }

  short8 qA[2], kA[2], qB[2], kB[2];
#define LOADQK(DQ, DK, KK) do {                                               \
    _Pragma("unroll")                                                         \
    for (int p = 0; p < 2; ++p) {                                             \
      const size_t foff = (size_t)p * 131072 + (size_t)ot * 8192 +            \
                          (size_t)(KK) * 1024 + (size_t)lane * 16;            \
      DQ[p] = *(const short8*)(wq + foff);                                    \
      DK[p] = *(const short8*)(wk + foff);                                    \
    }                                                                         \
  } while (0)
  // products small->large: wm*xh, wh*xm, wh*xh (identical order to R13-R16)
#define STEPQK(FQ, FK, KK) do {                                               \
    __builtin_amdgcn_s_setprio(1);                                            \
    _Pragma("unroll")                                                         \
    for (int nt = 0; nt < 4; ++nt) {                                          \
      const int boff = ((KK) * 4 + g) * XCH + (nt * 16 + ln) * 16;            \
      const short8 b0 = *(const short8*)(lds + LDS_X + boff);                 \
      const short8 b1 = *(const short8*)(lds + LDS_X + XPL + boff);           \
      aq[nt] = MFMA(FQ[1], b0, aq[nt], 0, 0, 0);                              \
      aq[nt] = MFMA(FQ[0], b1, aq[nt], 0, 0, 0);                              \
      aq[nt] = MFMA(FQ[0], b0, aq[nt], 0, 0, 0);                              \
      ak[nt] = MFMA(FK[1], b0, ak[nt], 0, 0, 0);                              \
      ak[nt] = MFMA(FK[0], b1, ak[nt], 0, 0, 0);                              \
      ak[nt] = MFMA(FK[0], b0, ak[nt], 0, 0, 0);                              \
    }                                                                         \
    __builtin_amdgcn_s_setprio(0);                                            \
  } while (0)

  LOADQK(qA, kA, 0);
  #pragma unroll 1
  for (int kk2 = 0; kk2 < 4; ++kk2) {
    const int kk = kk2 * 2;
    LOADQK(qB, kB, kk + 1);
    STEPQK(qA, kA, kk);
    if (kk2 < 3) LOADQK(qA, kA, kk + 2);
    STEPQK(qB, kB, kk + 1);
  }

  // ---- q epilogue: BN + push/pull LIF -> decision bits + coop rescue ----
  unsigned qeb = 0u, qib = 0u;   // spike bits, bit r*4+t
  #pragma unroll
  for (int r = 0; r < 4; ++r) {
    const int o = ot * 16 + g * 4 + r;
    const float inv = q_gamma[o] / sqrtf(q_var[o] + EPSF);
    const float mn = q_mean[o], bt = q_beta[o];
    float qv[4];
    #pragma unroll
    for (int t = 0; t < 4; ++t) qv[t] = (aq[t][r] - mn) * inv + bt;
    float se[4], si[4], mg = 1e30f;
    lif4m(qv[0], qv[1], qv[2], qv[3], 1.0f, se, mg);
    lif4m(-qv[0], -qv[1], -qv[2], -qv[3], 1.0f, si, mg);
    #pragma unroll
    for (int t = 0; t < 4; ++t) {
      qeb |= (se[t] != 0.f) ? (1u << (r * 4 + t)) : 0u;
      qib |= (si[t] != 0.f) ? (1u << (r * 4 + t)) : 0u;
    }
    // coop rescue for this r (wave-uniform entry; r is compile-time)
    const bool fl = (mg < EPS_R);
    const unsigned long long bal = __ballot(fl);
    if (__builtin_expect(bal != 0ull, 0)) {
      #pragma unroll 1
      for (int g2 = 0; g2 < 4; ++g2) {
        if (!((bal >> (g2 * 16)) & 0xFFFFull)) continue;
        const int o2 = ot * 16 + g2 * 4 + r;
        const float s = coop_chain(q_w + (size_t)o2 * CC, x, b, n0, lane);
        float qt[4];
        qt[0] = __shfl(s, ln);      qt[1] = __shfl(s, 16 + ln);
        qt[2] = __shfl(s, 32 + ln); qt[3] = __shfl(s, 48 + ln);
        if (g == g2 && fl) {
          float qv2[4];
          #pragma unroll
          for (int t = 0; t < 4; ++t) qv2[t] = (qt[t] - mn) * inv + bt;
          float se2[4], si2[4], m2 = 1e30f;
          lif4m(qv2[0], qv2[1], qv2[2], qv2[3], 1.0f, se2, m2);
          lif4m(-qv2[0], -qv2[1], -qv2[2], -qv2[3], 1.0f, si2, m2);
          #pragma unroll
          for (int t = 0; t < 4; ++t) {
            const unsigned bit = 1u << (r * 4 + t);
            qeb = (qeb & ~bit) | ((se2[t] != 0.f) ? bit : 0u);
            qib = (qib & ~bit) | ((si2[t] != 0.f) ? bit : 0u);
          }
        }
      }
    }
  }
  // dsum from bits (exact small ints), then reduce over the wave's 4 g-groups
  float dsum[4];
  #pragma unroll
  for (int t = 0; t < 4; ++t) {
    int v = 0;
    #pragma unroll
    for (int r = 0; r < 4; ++r)
      v += (int)((qeb >> (r * 4 + t)) & 1u) - (int)((qib >> (r * 4 + t)) & 1u);
    float fv = (float)v;
    fv += __shfl_xor(fv, 16);
    fv += __shfl_xor(fv, 32);
    dsum[t] = fv;
  }

  // ---- k epilogue: BN + LIF -> spike bits + coop rescue ----
  unsigned kb = 0u;   // bit r*4+t
  #pragma unroll
  for (int r = 0; r < 4; ++r) {
    const int o = ot * 16 + g * 4 + r;
    const float inv = k_gamma[o] / sqrtf(k_var[o] + EPSF);
    const float mn = k_mean[o], bt = k_beta[o];
    float kv[4];
    #pragma unroll
    for (int t = 0; t < 4; ++t) kv[t] = (ak[t][r] - mn) * inv + bt;
    float sk[4], mg = 1e30f;
    lif4m(kv[0], kv[1], kv[2], kv[3], 1.0f, sk, mg);
    #pragma unroll
    for (int t = 0; t < 4; ++t) kb |= (sk[t] != 0.f) ? (1u << (r * 4 + t)) : 0u;
    const bool fl = (mg < EPS_R);
    const unsigned long long bal = __ballot(fl);
    if (__builtin_expect(bal != 0ull, 0)) {
      #pragma unroll 1
      for (int g2 = 0; g2 < 4; ++g2) {
        if (!((bal >> (g2 * 16)) & 0xFFFFull)) continue;
        const int o2 = ot * 16 + g2 * 4 + r;
        const float s = coop_chain(k_w + (size_t)o2 * CC, x, b, n0, lane);
        float kt[4];
        kt[0] = __shfl(s, ln);      kt[1] = __shfl(s, 16 + ln);
        kt[2] = __shfl(s, 32 + ln); kt[3] = __shfl(s, 48 + ln);
        if (g == g2 && fl) {
          float kv2[4];
          #pragma unroll
          for (int t = 0; t < 4; ++t) kv2[t] = (kt[t] - mn) * inv + bt;
          float sk2[4], m2 = 1e30f;
          lif4m(kv2[0], kv2[1], kv2[2], kv2[3], 1.0f, sk2, m2);
          #pragma unroll
          for (int t = 0; t < 4; ++t) {
            const unsigned bit = 1u << (r * 4 + t);
            kb = (kb & ~bit) | ((sk2[t] != 0.f) ? bit : 0u);
          }
        }
      }
    }
  }

  // ---- head pair-reduce via LDS scratch (staging long finished) ----
  float* db = (float*)(lds + LDS_XF);   // [wave 16][ln 16][t 4]
  __syncthreads();                      // all plane-0/1 GEMM reads done
  if (g == 0) {
    #pragma unroll
    for (int t = 0; t < 4; ++t) db[(ot * 16 + ln) * 4 + t] = dsum[t];
  }
  __syncthreads();
  float at[4];
  {
    float tot[4];
    #pragma unroll
    for (int t = 0; t < 4; ++t)
      tot[t] = dsum[t] + db[((ot ^ 1) * 16 + ln) * 4 + t];   // exact ints
    float mgd = 1e30f;
    lif4m(tot[0], tot[1], tot[2], tot[3], 0.5f, at, mgd);    // exact dyadics
  }

  // ---- x_one = attn & k_s (binary bf16) -> plane 0 ----
  {
    const int chunk = ot * 2 + (g >> 1);
    const int j0 = (g & 1) * 4;
    #pragma unroll
    for (int t = 0; t < 4; ++t) {
      unsigned long long wbits = 0ull;
      #pragma unroll
      for (int r = 0; r < 4; ++r)
        if (((kb >> (r * 4 + t)) & 1u) && at[t] != 0.f)
          wbits |= 0x3F80ull << (r * 16);
      *(unsigned long long*)(lds + LDS_X + chunk * XCH +
                             (t * 16 + ln) * 16 + j0 * 2) = wbits;
    }
  }
  __syncthreads();   // x_one visible

  // ====== proj GEMM: 2 products {wm, wh} x binary x_one (plane 0) ======
  f32x4 ap[4];
  #pragma unroll
  for (int nt = 0; nt < 4; ++nt) ap[nt] = (f32x4)0.f;

  short8 pA[2], pB[2];
#define LOADP(DP, KK) do {                                                    \
    _Pragma("unroll")                                                         \
    for (int p = 0; p < 2; ++p)                                               \
      DP[p] = *(const short8*)(wp + (size_t)p * 131072 + (size_t)ot * 8192 +  \
                               (size_t)(KK) * 1024 + (size_t)lane * 16);      \
  } while (0)
#define STEPP(FP, KK) do {                                                    \
    __builtin_amdgcn_s_setprio(1);                                            \
    _Pragma("unroll")                                                         \
    for (int nt = 0; nt < 4; ++nt) {                                          \
      const short8 b0 = *(const short8*)(lds + LDS_X +                        \
                        ((KK) * 4 + g) * XCH + (nt * 16 + ln) * 16);          \
      ap[nt] = MFMA(FP[1], b0, ap[nt], 0, 0, 0);                              \
      ap[nt] = MFMA(FP[0], b0, ap[nt], 0, 0, 0);                              \
    }                                                                         \
    __builtin_amdgcn_s_setprio(0);                                            \
  } while (0)

  LOADP(pA, 0);
  #pragma unroll 1
  for (int kk2 = 0; kk2 < 4; ++kk2) {
    const int kk = kk2 * 2;
    LOADP(pB, kk + 1);
    STEPP(pA, kk);
    if (kk2 < 3) LOADP(pA, kk + 2);
    STEPP(pB, kk + 1);
  }

  // ---- proj epilogue: bias + BN + LIF (+LDS rescue) + store ----
  #pragma unroll
  for (int r = 0; r < 4; ++r) {
    const int o = ot * 16 + g * 4 + r;
    const float inv = p_gamma[o] / sqrtf(p_var[o] + EPSF);
    const float mn = p_mean[o], bt = p_beta[o], pb = proj_b[o];
    float pv[4];
    #pragma unroll
    for (int t = 0; t < 4; ++t) pv[t] = ((ap[t][r] + pb) - mn) * inv + bt;
    float sp[4], mg = 1e30f;
    lif4m(pv[0], pv[1], pv[2], pv[3], 1.0f, sp, mg);
    if (__builtin_expect(mg < EPS_R, 0)) {
      float px[4];
      rescue1(proj_w + (size_t)o * CC, lds, ln, px);
      #pragma unroll
      for (int t = 0; t < 4; ++t) px[t] = ((px[t] + pb) - mn) * inv + bt;
      float m2 = 1e30f;
      lif4m(px[0], px[1], px[2], px[3], 1.0f, sp, m2);
    }
    #pragma unroll
    for (int t = 0; t < 4; ++t)
      out[((size_t)(t * BB + b) * CC + o) * NN + n0 + ln] = sp[t];
  }
}

extern "C" void kernel_launch(void* const* d_in, const int* in_sizes, int n_in,
                              void* d_out, int out_size, void* d_ws, size_t ws_size,
                              hipStream_t stream) {
  const float* x       = (const float*)d_in[0];
  const float* q_w     = (const float*)d_in[1];
  const float* q_gamma = (const float*)d_in[2];
  const float* q_beta  = (const float*)d_in[3];
  const float* q_mean  = (const float*)d_in[4];
  const float* q_var   = (const float*)d_in[5];
  const float* k_w     = (const float*)d_in[6];
  const float* k_gamma = (const float*)d_in[7];
  const float* k_beta  = (const float*)d_in[8];
  const float* k_mean  = (const float*)d_in[9];
  const float* k_var   = (const float*)d_in[10];
  const float* proj_w  = (const float*)d_in[11];
  const float* proj_b  = (const float*)d_in[12];
  const float* p_gamma = (const float*)d_in[13];
  const float* p_beta  = (const float*)d_in[14];
  const float* p_mean  = (const float*)d_in[15];
  const float* p_var   = (const float*)d_in[16];
  float* out = (float*)d_out;
  uint16_t* wsp = (uint16_t*)d_ws;   // 1.125 MB split-weight fragment planes

  wsplit2<<<96, 256, 0, stream>>>(q_w, k_w, proj_w, wsp);
  pushpull_mfma10<<<BB * (NN / NT), 1024, 0, stream>>>(
      x, q_w, q_gamma, q_beta, q_mean, q_var,
      k_w, k_gamma, k_beta, k_mean, k_var,
      proj_w, proj_b, p_gamma, p_beta, p_mean, p_var, wsp, out);
}